// Round 14
// baseline (2595.309 us; speedup 1.0000x reference)
//
#include <hip/hip_runtime.h>
#include <hip/hip_bf16.h>

#define BN 32
#define CC 128
#define NN 2025
#define KK 9
#define NGROUP 4
#define CPG 32
#define GN_EPS 1e-5f
#define ROWS_TOTAL (BN * NN)   // 64800

typedef _Float16 f16;
typedef __attribute__((ext_vector_type(8))) _Float16 f16x8;
typedef __attribute__((ext_vector_type(4))) float f32x4;

#define S28 3.725290298461914e-09f   // 2^-28  (xh*wh)
#define S40 9.094947017729282e-13f   // 2^-40  (xh*wl + xl*wh)
#define S26 1.4901161193847656e-08f  // 2^-26  (vh*wh, layer2)
#define S38 3.637978807091713e-12f   // 2^-38  (vh*wl + vl*wh, layer2)

#define T0F 0.17f                    // survivor threshold (9th-best ~0.23, min ~0.19)
#define CAP 100                      // per-row survivor capacity (mean ~55, max ~95; overflow -> exact fallback)

#define GN_INV (1.0f / (float)(NN * CPG))

// ---------------- Kernel 1: L2 normalize -> scaled f16 split (R10 transpose version) ----------------
__global__ __launch_bounds__(256) void k_normalize(const float* __restrict__ x,
                                                   f16* __restrict__ xh, f16* __restrict__ xl) {
    __shared__ float tile[128][65];
    const int b  = blockIdx.y;
    const int n0 = blockIdx.x * 64;
    const int t  = threadIdx.x;
    const int w  = t >> 6;
    const int lane = t & 63;
    const int gn_ld = min(n0 + lane, NN - 1);   // tail clamp (dup value, never stored)

    for (int it = 0; it < 32; ++it) {
        int c = it * 4 + w;
        tile[c][lane] = x[((size_t)(b * CC + c)) * NN + gn_ld];
    }
    __syncthreads();

    for (int i = 0; i < 16; ++i) {
        int n  = w * 16 + i;
        int gn = n0 + n;
        if (gn < NN) {
            float v0 = tile[lane][n];
            float v1 = tile[lane + 64][n];
            float ss = v0 * v0 + v1 * v1;
#pragma unroll
            for (int off = 32; off > 0; off >>= 1) ss += __shfl_xor(ss, off);
            float s = 1.0f / fmaxf(sqrtf(ss), 1e-12f);
            v0 *= s; v1 *= s;
            float w0 = v0 * 16384.0f, w1 = v1 * 16384.0f;
            f16 h0 = (f16)w0, h1 = (f16)w1;
            f16 l0 = (f16)((w0 - (float)h0) * 4096.0f);
            f16 l1 = (f16)((w1 - (float)h1) * 4096.0f);
            size_t base = (size_t)(b * NN + gn) * CC;
            xh[base + lane] = h0;  xh[base + lane + 64] = h1;
            xl[base + lane] = l0;  xl[base + lane + 64] = l1;
        }
    }
}

// top-9 insert: (value desc, index asc) ordering; order-independent tie rules — EXACT
__device__ __forceinline__ void ins9(float cand, int m, float* v, int* ix,
                                     float& mv, int& mi, int& mp) {
    bool take = (cand > mv) || ((cand == mv) && (m < mi));
    if (take) {
#pragma unroll
        for (int k = 0; k < 9; ++k) if (k == mp) { v[k] = cand; ix[k] = m; }
        float nv = v[0]; int ni = ix[0]; int np = 0;
#pragma unroll
        for (int k = 1; k < 9; ++k) {
            if (v[k] < nv || (v[k] == nv && ix[k] > ni)) { nv = v[k]; ni = ix[k]; np = k; }
        }
        mv = nv; mi = ni; mp = np;
    }
}

// ---------------- Kernel 2: fused sim + top-k (R9 structure FROZEN) ----------------
__global__ __launch_bounds__(256) void k_sim_topk(const f16* __restrict__ xh, const f16* __restrict__ xl,
                                                  float* __restrict__ vout, unsigned short* __restrict__ iout) {
    __shared__ f16x8          stg[2][32][16];  // 16KB staged 32-m window: [hl][row][frag^(row&7)]
    __shared__ float          sv[32][CAP + 1];
    __shared__ unsigned short si[32][CAP + 2];
    __shared__ int   cnt[32];
    __shared__ int   nbad;
    __shared__ int   badrows[32];

    const int id   = blockIdx.x;                  // 0..2047
    const int b    = (id & 7) + 8 * (id >> 9);
    const int r0   = ((id >> 3) & 63) * 32;
    const int t    = threadIdx.x;
    const int w    = t >> 6;
    const int lane = t & 63;
    const int jr   = lane & 15;
    const int q    = lane >> 4;
    const int tw   = w & 1;
    const int mh   = w >> 1;

    if (t < 32) cnt[t] = 0;
    if (t == 0) nbad = 0;

    f16x8 bh[4], bl[4];
    {
        int rr = b * NN + min(r0 + tw * 16 + jr, NN - 1);
        const f16* pH = xh + (size_t)rr * CC;
        const f16* pL = xl + (size_t)rr * CC;
#pragma unroll
        for (int s = 0; s < 4; ++s) {
            bh[s] = *(const f16x8*)(pH + s * 32 + q * 8);
            bl[s] = *(const f16x8*)(pL + s * 32 + q * 8);
        }
    }

    const int fi_ = t & 15;
    const int ri_ = t >> 4;
    const int fx  = fi_ ^ (ri_ & 7);
    const int rbuf = tw * 16 + jr;

    f16x8 h0r, h1r, l0r, l1r;
    {
        size_t g0 = (size_t)(b * NN + min(ri_, NN - 1)) * CC + fi_ * 8;
        size_t g1 = (size_t)(b * NN + min(ri_ + 16, NN - 1)) * CC + fi_ * 8;
        h0r = *(const f16x8*)(xh + g0);  h1r = *(const f16x8*)(xh + g1);
        l0r = *(const f16x8*)(xl + g0);  l1r = *(const f16x8*)(xl + g1);
    }

    for (int chunk = 0; chunk < 64; ++chunk) {
        __syncthreads();
        stg[0][ri_][fx]      = h0r;
        stg[0][ri_ + 16][fx] = h1r;
        stg[1][ri_][fx]      = l0r;
        stg[1][ri_ + 16][fx] = l1r;
        __syncthreads();
        if (chunk < 63) {
            size_t g0 = (size_t)(b * NN + min((chunk + 1) * 32 + ri_, NN - 1)) * CC + fi_ * 8;
            size_t g1 = (size_t)(b * NN + min((chunk + 1) * 32 + ri_ + 16, NN - 1)) * CC + fi_ * 8;
            h0r = *(const f16x8*)(xh + g0);  h1r = *(const f16x8*)(xh + g1);
            l0r = *(const f16x8*)(xl + g0);  l1r = *(const f16x8*)(xl + g1);
        }
        __builtin_amdgcn_sched_barrier(0);

        const int mb   = chunk * 32 + mh * 16;
        const int arow = mh * 16 + jr;
        const int axr  = arow & 7;
        f32x4 hh = {0.f, 0.f, 0.f, 0.f}, ll = {0.f, 0.f, 0.f, 0.f};
#pragma unroll
        for (int s = 0; s < 4; ++s) {
            f16x8 ah = stg[0][arow][(s * 4 + q) ^ axr];
            f16x8 al = stg[1][arow][(s * 4 + q) ^ axr];
            hh = __builtin_amdgcn_mfma_f32_16x16x32_f16(ah, bh[s], hh, 0, 0, 0);
            ll = __builtin_amdgcn_mfma_f32_16x16x32_f16(ah, bl[s], ll, 0, 0, 0);
            ll = __builtin_amdgcn_mfma_f32_16x16x32_f16(al, bh[s], ll, 0, 0, 0);
        }
#pragma unroll
        for (int reg = 0; reg < 4; ++reg) {
            int m = mb + q * 4 + reg;
            float c0 = hh[reg] * S28 + ll[reg] * S40;
            if (m < NN && c0 > T0F) {
                int pos = atomicAdd(&cnt[rbuf], 1);
                if (pos < CAP) { sv[rbuf][pos] = c0; si[rbuf][pos] = (unsigned short)m; }
            }
        }
    }
    __syncthreads();

    if (t < 32) {
        int r = r0 + t;
        if (r < NN) {
            int c = cnt[t];
            if (c >= 9 && c <= CAP) {
                float fv[9]; int fi[9];
#pragma unroll
                for (int k = 0; k < 9; ++k) { fv[k] = -3.0e38f; fi[k] = 0x7fffffff; }
                float mv = -3.0e38f; int mi = 0x7fffffff; int mp = 0;
                for (int j = 0; j < c; ++j) ins9(sv[t][j], (int)si[t][j], fv, fi, mv, mi, mp);
                float s = 1e-6f;
#pragma unroll
                for (int k = 0; k < 9; ++k) s += fv[k];
                float inv = 1.0f / s;
                int base = (b * NN + r) * KK;
#pragma unroll
                for (int k = 0; k < 9; ++k) { vout[base + k] = fv[k] * inv; iout[base + k] = (unsigned short)fi[k]; }
            } else {
                int slot = atomicAdd(&nbad, 1);
                badrows[slot] = r;
            }
        }
    }
    __syncthreads();

    if (w == 0) {
        int nb = nbad;
        for (int ib = 0; ib < nb; ++ib) {
            int r = badrows[ib];
            const f16* rH = xh + ((size_t)b * NN + r) * CC;
            const f16* rL = xl + ((size_t)b * NN + r) * CC;
            float fv[9]; int fi[9];
#pragma unroll
            for (int k = 0; k < 9; ++k) { fv[k] = -3.0e38f; fi[k] = 0x7fffffff; }
            float mv = -3.0e38f; int mi = 0x7fffffff; int mp = 0;
            for (int m = lane; m < NN; m += 64) {
                const f16* mH = xh + ((size_t)b * NN + m) * CC;
                const f16* mL = xl + ((size_t)b * NN + m) * CC;
                float a1 = 0.f, a2 = 0.f;
                for (int c2 = 0; c2 < CC; ++c2) {
                    float hr = (float)rH[c2], hm = (float)mH[c2];
                    float lr = (float)rL[c2], lm = (float)mL[c2];
                    a1 += hr * hm;
                    a2 += hr * lm + lr * hm;
                }
                ins9(a1 * S28 + a2 * S40, m, fv, fi, mv, mi, mp);
            }
#pragma unroll
            for (int off = 1; off < 64; off <<= 1) {
                float pv[9]; int pi[9];
#pragma unroll
                for (int k = 0; k < 9; ++k) { pv[k] = __shfl_xor(fv[k], off); pi[k] = __shfl_xor(fi[k], off); }
#pragma unroll
                for (int k = 0; k < 9; ++k) ins9(pv[k], pi[k], fv, fi, mv, mi, mp);
            }
            if (lane == 0) {
                float s = 1e-6f;
#pragma unroll
                for (int k = 0; k < 9; ++k) s += fv[k];
                float inv = 1.0f / s;
                int base = (b * NN + r) * KK;
#pragma unroll
                for (int k = 0; k < 9; ++k) { vout[base + k] = fv[k] * inv; iout[base + k] = (unsigned short)fi[k]; }
            }
        }
    }
}

// ---------------- Kernel 3pre: weight transpose/split + zero the GN sum accumulators ----------------
__global__ __launch_bounds__(256) void k_wsplit(const float* __restrict__ w1, const float* __restrict__ w2,
                                                f16* __restrict__ wth1, f16* __restrict__ wtl1,
                                                f16* __restrict__ wth2, f16* __restrict__ wtl2,
                                                float* __restrict__ ssum1, float* __restrict__ ssum2) {
    // zero this layer's GN sum accumulator (re-zeroed every launch, before any gather)
    float* z = blockIdx.x ? ssum2 : ssum1;
    if (threadIdx.x < 2 * BN * NGROUP) z[threadIdx.x] = 0.0f;

    const float* w = blockIdx.x ? w2 : w1;
    f16* th = blockIdx.x ? wth2 : wth1;
    f16* tl = blockIdx.x ? wtl2 : wtl1;
    for (int e = threadIdx.x; e < CC * CC; e += 256) {
        int c = e >> 7, j = e & 127;
        float ws_ = w[e] * 16384.0f;
        f16 h = (f16)ws_;
        f16 l = (f16)((ws_ - (float)h) * 4096.0f);
        th[j * CC + c] = h;
        tl[j * CC + c] = l;
    }
}

// ---------------- Kernel 3: tiled MFMA split GEMM, 128 rows/block, LDS-staged A ----------------
__global__ __launch_bounds__(256) void k_gemm_tile(const f16* __restrict__ ah, const f16* __restrict__ al,
                                                   const f16* __restrict__ wth, const f16* __restrict__ wtl,
                                                   float sH, float sL, f16* __restrict__ out) {
    __shared__ f16x8 stg[2][32][16];   // [hl][row][frag^(row&7)] — sim_topk layout
    const int t    = threadIdx.x;
    const int w    = t >> 6;
    const int lane = t & 63;
    const int jr   = lane & 15;
    const int q    = lane >> 4;
    const int row0 = blockIdx.x * 128;

    f16x8 wbh[2][4], wbl[2][4];
#pragma unroll
    for (int ct = 0; ct < 2; ++ct) {
        int j = w * 32 + ct * 16 + jr;
        const f16* pH = wth + (size_t)j * CC;
        const f16* pL = wtl + (size_t)j * CC;
#pragma unroll
        for (int s = 0; s < 4; ++s) {
            wbh[ct][s] = *(const f16x8*)(pH + s * 32 + q * 8);
            wbl[ct][s] = *(const f16x8*)(pL + s * 32 + q * 8);
        }
    }

    const int fi_ = t & 15;
    const int ri_ = t >> 4;
    const int fx  = fi_ ^ (ri_ & 7);

    f16x8 h0r, h1r, l0r, l1r;
    {
        size_t g0 = (size_t)min(row0 + ri_, ROWS_TOTAL - 1) * CC + fi_ * 8;
        size_t g1 = (size_t)min(row0 + ri_ + 16, ROWS_TOTAL - 1) * CC + fi_ * 8;
        h0r = *(const f16x8*)(ah + g0);  h1r = *(const f16x8*)(ah + g1);
        l0r = *(const f16x8*)(al + g0);  l1r = *(const f16x8*)(al + g1);
    }

    for (int chunk = 0; chunk < 4; ++chunk) {
        __syncthreads();
        stg[0][ri_][fx]      = h0r;
        stg[0][ri_ + 16][fx] = h1r;
        stg[1][ri_][fx]      = l0r;
        stg[1][ri_ + 16][fx] = l1r;
        __syncthreads();
        if (chunk < 3) {
            size_t g0 = (size_t)min(row0 + (chunk + 1) * 32 + ri_, ROWS_TOTAL - 1) * CC + fi_ * 8;
            size_t g1 = (size_t)min(row0 + (chunk + 1) * 32 + ri_ + 16, ROWS_TOTAL - 1) * CC + fi_ * 8;
            h0r = *(const f16x8*)(ah + g0);  h1r = *(const f16x8*)(ah + g1);
            l0r = *(const f16x8*)(al + g0);  l1r = *(const f16x8*)(al + g1);
        }
        __builtin_amdgcn_sched_barrier(0);

#pragma unroll
        for (int rt = 0; rt < 2; ++rt) {
            const int arow = rt * 16 + jr;
            const int axr  = arow & 7;
            f16x8 af[4], alf[4];
#pragma unroll
            for (int s = 0; s < 4; ++s) {
                af[s]  = stg[0][arow][(s * 4 + q) ^ axr];
                alf[s] = stg[1][arow][(s * 4 + q) ^ axr];
            }
            f32x4 hh0 = {0.f,0.f,0.f,0.f}, ll0 = {0.f,0.f,0.f,0.f};
            f32x4 hh1 = {0.f,0.f,0.f,0.f}, ll1 = {0.f,0.f,0.f,0.f};
#pragma unroll
            for (int s = 0; s < 4; ++s) {
                hh0 = __builtin_amdgcn_mfma_f32_16x16x32_f16(af[s],  wbh[0][s], hh0, 0, 0, 0);
                ll0 = __builtin_amdgcn_mfma_f32_16x16x32_f16(af[s],  wbl[0][s], ll0, 0, 0, 0);
                ll0 = __builtin_amdgcn_mfma_f32_16x16x32_f16(alf[s], wbh[0][s], ll0, 0, 0, 0);
                hh1 = __builtin_amdgcn_mfma_f32_16x16x32_f16(af[s],  wbh[1][s], hh1, 0, 0, 0);
                ll1 = __builtin_amdgcn_mfma_f32_16x16x32_f16(af[s],  wbl[1][s], ll1, 0, 0, 0);
                ll1 = __builtin_amdgcn_mfma_f32_16x16x32_f16(alf[s], wbh[1][s], ll1, 0, 0, 0);
            }
#pragma unroll
            for (int reg = 0; reg < 4; ++reg) {
                int orow = row0 + chunk * 32 + rt * 16 + q * 4 + reg;
                if (orow < ROWS_TOTAL) {
                    size_t ob = (size_t)orow * CC + w * 32 + jr;
                    out[ob]      = (f16)(hh0[reg] * sH + ll0[reg] * sL);
                    out[ob + 16] = (f16)(hh1[reg] * sH + ll1[reg] * sL);
                }
            }
        }
    }
}

// ---------------- Kernel 3b: tiled GEMM with GN+SiLU+split fused into A-staging ----------------
// R14: mean/rstd computed inline from the gather-accumulated (s1,s2) sums.
__global__ __launch_bounds__(256) void k_gemm_tile_gn(const f16* __restrict__ act,
                                                      const float* __restrict__ ssum,
                                                      const float* __restrict__ gamma,
                                                      const float* __restrict__ beta,
                                                      const f16* __restrict__ wth, const f16* __restrict__ wtl,
                                                      float sH, float sL, f16* __restrict__ out) {
    __shared__ f16x8 stg[2][32][16];
    const int t    = threadIdx.x;
    const int w    = t >> 6;
    const int lane = t & 63;
    const int jr   = lane & 15;
    const int q    = lane >> 4;
    const int row0 = blockIdx.x * 128;

    f16x8 wbh[2][4], wbl[2][4];
#pragma unroll
    for (int ct = 0; ct < 2; ++ct) {
        int j = w * 32 + ct * 16 + jr;
        const f16* pH = wth + (size_t)j * CC;
        const f16* pL = wtl + (size_t)j * CC;
#pragma unroll
        for (int s = 0; s < 4; ++s) {
            wbh[ct][s] = *(const f16x8*)(pH + s * 32 + q * 8);
            wbl[ct][s] = *(const f16x8*)(pL + s * 32 + q * 8);
        }
    }

    const int fi_ = t & 15;
    const int ri_ = t >> 4;
    const int fx  = fi_ ^ (ri_ & 7);
    const int gg  = fi_ >> 2;          // group of this thread's 8-channel slice

    float gma[8], bta[8];
#pragma unroll
    for (int e = 0; e < 8; ++e) { gma[e] = gamma[fi_ * 8 + e]; bta[e] = beta[fi_ * 8 + e]; }

    f16x8 pa, pb;
    int ra = min(row0 + ri_, ROWS_TOTAL - 1);
    int rb = min(row0 + ri_ + 16, ROWS_TOTAL - 1);
    pa = *(const f16x8*)(act + (size_t)ra * CC + fi_ * 8);
    pb = *(const f16x8*)(act + (size_t)rb * CC + fi_ * 8);

    for (int chunk = 0; chunk < 4; ++chunk) {
        __syncthreads();
        {
            int ba = ra / NN, bb = rb / NN;
            float sa1 = ssum[(ba * 4 + gg) * 2], sa2 = ssum[(ba * 4 + gg) * 2 + 1];
            float sb1 = ssum[(bb * 4 + gg) * 2], sb2 = ssum[(bb * 4 + gg) * 2 + 1];
            float ma  = sa1 * GN_INV;
            float rsa = rsqrtf(fmaxf(sa2 * GN_INV - ma * ma, 0.f) + GN_EPS);
            float mb  = sb1 * GN_INV;
            float rsb = rsqrtf(fmaxf(sb2 * GN_INV - mb * mb, 0.f) + GN_EPS);
            f16x8 hva, lva, hvb, lvb;
#pragma unroll
            for (int e = 0; e < 8; ++e) {
                float ya = ((float)pa[e] - ma) * rsa * gma[e] + bta[e];
                float ra_ = ya / (1.0f + expf(-ya));
                float sa = ra_ * 4096.0f;
                f16 h = (f16)sa; hva[e] = h; lva[e] = (f16)((sa - (float)h) * 4096.0f);
                float yb = ((float)pb[e] - mb) * rsb * gma[e] + bta[e];
                float rb_ = yb / (1.0f + expf(-yb));
                float sb = rb_ * 4096.0f;
                f16 h2 = (f16)sb; hvb[e] = h2; lvb[e] = (f16)((sb - (float)h2) * 4096.0f);
            }
            stg[0][ri_][fx]      = hva;
            stg[0][ri_ + 16][fx] = hvb;
            stg[1][ri_][fx]      = lva;
            stg[1][ri_ + 16][fx] = lvb;
        }
        __syncthreads();
        if (chunk < 3) {
            ra = min(row0 + (chunk + 1) * 32 + ri_, ROWS_TOTAL - 1);
            rb = min(row0 + (chunk + 1) * 32 + ri_ + 16, ROWS_TOTAL - 1);
            pa = *(const f16x8*)(act + (size_t)ra * CC + fi_ * 8);
            pb = *(const f16x8*)(act + (size_t)rb * CC + fi_ * 8);
        }
        __builtin_amdgcn_sched_barrier(0);

#pragma unroll
        for (int rt = 0; rt < 2; ++rt) {
            const int arow = rt * 16 + jr;
            const int axr  = arow & 7;
            f16x8 af[4], alf[4];
#pragma unroll
            for (int s = 0; s < 4; ++s) {
                af[s]  = stg[0][arow][(s * 4 + q) ^ axr];
                alf[s] = stg[1][arow][(s * 4 + q) ^ axr];
            }
            f32x4 hh0 = {0.f,0.f,0.f,0.f}, ll0 = {0.f,0.f,0.f,0.f};
            f32x4 hh1 = {0.f,0.f,0.f,0.f}, ll1 = {0.f,0.f,0.f,0.f};
#pragma unroll
            for (int s = 0; s < 4; ++s) {
                hh0 = __builtin_amdgcn_mfma_f32_16x16x32_f16(af[s],  wbh[0][s], hh0, 0, 0, 0);
                ll0 = __builtin_amdgcn_mfma_f32_16x16x32_f16(af[s],  wbl[0][s], ll0, 0, 0, 0);
                ll0 = __builtin_amdgcn_mfma_f32_16x16x32_f16(alf[s], wbh[0][s], ll0, 0, 0, 0);
                hh1 = __builtin_amdgcn_mfma_f32_16x16x32_f16(af[s],  wbh[1][s], hh1, 0, 0, 0);
                ll1 = __builtin_amdgcn_mfma_f32_16x16x32_f16(af[s],  wbl[1][s], ll1, 0, 0, 0);
                ll1 = __builtin_amdgcn_mfma_f32_16x16x32_f16(alf[s], wbh[1][s], ll1, 0, 0, 0);
            }
#pragma unroll
            for (int reg = 0; reg < 4; ++reg) {
                int orow = row0 + chunk * 32 + rt * 16 + q * 4 + reg;
                if (orow < ROWS_TOTAL) {
                    size_t ob = (size_t)orow * CC + w * 32 + jr;
                    out[ob]      = (f16)(hh0[reg] * sH + ll0[reg] * sL);
                    out[ob + 16] = (f16)(hh1[reg] * sH + ll1[reg] * sL);
                }
            }
        }
    }
}

// ---------------- Kernel 4: gather + weighted sum + bias + GN-stat accumulation ----------------
// R14: per-32-lane (one GN group) shuffle reduction of (q, q^2) then 2 atomicAdds/segment.
// q is the QUANTIZED stored value => stats match R13's gnstats up to summation order.
__global__ __launch_bounds__(256) void k_gather_st(const f16* __restrict__ xt,
                                                   const float* __restrict__ v,
                                                   const unsigned short* __restrict__ idx,
                                                   const float* __restrict__ bias,
                                                   f16* __restrict__ out,
                                                   float* __restrict__ ssum) {
    int t = threadIdx.x;
    int g = blockIdx.x * 2 + (t >> 7);
    int c = t & 127;
    if (g >= ROWS_TOTAL) return;
    int b = g / NN;
    int nb = b * NN;
    float acc = bias[c];
    int base = g * KK;
#pragma unroll
    for (int k = 0; k < KK; ++k) {
        int   ii = (int)idx[base + k];
        float vv = v[base + k];
        acc += vv * (float)xt[(size_t)(nb + ii) * CC + c];
    }
    f16 qo = (f16)acc;
    out[(size_t)g * CC + c] = qo;

    // GN stats: reduce over the 32-lane group (c>>5 constant within it)
    float q1 = (float)qo;
    float q2 = q1 * q1;
#pragma unroll
    for (int off = 16; off > 0; off >>= 1) {
        q1 += __shfl_xor(q1, off);
        q2 += __shfl_xor(q2, off);
    }
    if (((t & 63) & 31) == 0) {
        int sidx = (b * 4 + (c >> 5)) * 2;
        atomicAdd(&ssum[sidx], q1);
        atomicAdd(&ssum[sidx + 1], q2);
    }
}

// ---------------- Kernel 7: GN apply + SiLU + transpose to [B][C][N] — sums -> stats inline ----------------
__global__ __launch_bounds__(256) void k_gnsilu_out(const f16* __restrict__ xin,
                                                    const float* __restrict__ ssum,
                                                    const float* __restrict__ gamma,
                                                    const float* __restrict__ beta,
                                                    float* __restrict__ out) {
    __shared__ float tile[32 * 65];
    int b = blockIdx.z, ct = blockIdx.y, nt = blockIdx.x;
    int c0 = ct * 32, n0 = nt * 64;
    int t = threadIdx.x;
    int cj = t & 31, ni0 = t >> 5;
    int gg = c0 >> 5;
    float s1 = ssum[(b * 4 + gg) * 2];
    float s2 = ssum[(b * 4 + gg) * 2 + 1];
    float mean = s1 * GN_INV;
    float rstd = rsqrtf(fmaxf(s2 * GN_INV - mean * mean, 0.f) + GN_EPS);
    float gm = gamma[c0 + cj];
    float bt = beta[c0 + cj];
#pragma unroll
    for (int i = 0; i < 8; ++i) {
        int n = n0 + ni0 + i * 8;
        if (n < NN) {
            float x = (float)xin[((size_t)b * NN + n) * CC + c0 + cj];
            float y = (x - mean) * rstd * gm + bt;
            y = y / (1.0f + expf(-y));
            tile[cj * 65 + ni0 + i * 8] = y;
        }
    }
    __syncthreads();
    int nj = t & 63, ci0 = t >> 6;
#pragma unroll
    for (int i = 0; i < 8; ++i) {
        int c = ci0 + i * 4;
        int n = n0 + nj;
        if (n < NN) out[((size_t)b * CC + c0 + c) * NN + n] = tile[c * 65 + nj];
    }
}

extern "C" void kernel_launch(void* const* d_in, const int* in_sizes, int n_in,
                              void* d_out, int out_size, void* d_ws, size_t ws_size,
                              hipStream_t stream) {
    const float* x      = (const float*)d_in[0];
    const float* w1     = (const float*)d_in[1];
    const float* b1     = (const float*)d_in[2];
    const float* w2     = (const float*)d_in[3];
    const float* b2     = (const float*)d_in[4];
    const float* gamma1 = (const float*)d_in[5];
    const float* beta1  = (const float*)d_in[6];
    const float* gamma2 = (const float*)d_in[7];
    const float* beta2  = (const float*)d_in[8];
    float* out = (float*)d_out;

    const size_t BIG = (size_t)ROWS_TOTAL * CC;   // 8,294,400
    const size_t RK  = (size_t)ROWS_TOTAL * KK;   // 583,200
    float* ws   = (float*)d_ws;
    f16*   bufB_h = (f16*)ws;                      // gemm1 out / gather1 in; gemm2 out / gather2 in
    f16*   xh   = (f16*)(ws + BIG);
    f16*   xl   = xh + BIG;
    f16*   bufA_h = (f16*)(ws + BIG);              // gather1 out (aliases xh, dead after gemm1); gather2 out
    float* vbuf = ws + 2 * BIG;
    unsigned short* ibuf = (unsigned short*)(ws + 2 * BIG + RK);
    f16*   wth1 = (f16*)(ws + 2 * BIG + RK + RK / 2);
    f16*   wtl1 = wth1 + CC * CC;
    f16*   wth2 = wtl1 + CC * CC;
    f16*   wtl2 = wth2 + CC * CC;
    float* ssum1 = ws + 2 * BIG + RK + RK / 2 + 2 * CC * CC;   // [BN*NGROUP*2]
    float* ssum2 = ssum1 + 2 * BN * NGROUP;

    const int GB = (ROWS_TOTAL + 127) / 128;      // 507 gemm blocks

    k_normalize<<<dim3(32, BN), 256, 0, stream>>>(x, xh, xl);
    k_wsplit<<<2, 256, 0, stream>>>(w1, w2, wth1, wtl1, wth2, wtl2, ssum1, ssum2);
    k_sim_topk<<<2048, 256, 0, stream>>>(xh, xl, vbuf, ibuf);

    // layer 1 (xh/xl last read by gemm1; bufA_h aliases xh, written by gather1 after)
    k_gemm_tile<<<GB, 256, 0, stream>>>(xh, xl, wth1, wtl1, S28, S40, bufB_h);
    k_gather_st<<<ROWS_TOTAL / 2, 256, 0, stream>>>(bufB_h, vbuf, ibuf, b1, bufA_h, ssum1);

    // layer 2: GN+SiLU fused into gemm2's A-staging (stats from ssum1 inline)
    k_gemm_tile_gn<<<GB, 256, 0, stream>>>(bufA_h, ssum1, gamma1, beta1, wth2, wtl2, S26, S38, bufB_h);
    k_gather_st<<<ROWS_TOTAL / 2, 256, 0, stream>>>(bufB_h, vbuf, ibuf, b2, bufA_h, ssum2);
    k_gnsilu_out<<<dim3((NN + 63) / 64, NGROUP, BN), 256, 0, stream>>>(bufA_h, ssum2, gamma2, beta2, out);
}